// Round 14
// baseline (212.867 us; speedup 1.0000x reference)
//
#include <hip/hip_runtime.h>
#include <stdint.h>

#define Bv 8
#define Cv 64
#define Lv 65536
#define TPB 256
#define HALF 128                      // cols per half-tile
#define COLS 256                      // cols per block (2 halves)
#define BLKS_PER_B (Lv / COLS)        // 256
#define GRID1 (Bv * BLKS_PER_B)       // 2048

// workspace: partials 2*2048 floats (16 KiB) + sb 1024 floats (4 KiB) = 20 KiB

typedef __attribute__((ext_vector_type(8))) short short8;
typedef __attribute__((ext_vector_type(4))) float f32x4;

#define SSTRIDE 132   // dwords per row

__device__ __forceinline__ uint16_t f2bf(float f) {
    uint32_t u = __float_as_uint(f);
    uint32_t r = u + 0x7FFFu + ((u >> 16) & 1u);   // round-to-nearest-even
    return (uint16_t)(r >> 16);
}
__device__ __forceinline__ uint32_t pack2bf(float lo, float hi) {
    return (uint32_t)f2bf(lo) | ((uint32_t)f2bf(hi) << 16);
}
// load 8 consecutive fp32 weights -> one bf16 A-fragment (4 dwords)
__device__ __forceinline__ uint4 load_wfrag(const float* wp) {
    const float4 f0 = *reinterpret_cast<const float4*>(wp);
    const float4 f1 = *reinterpret_cast<const float4*>(wp + 4);
    uint4 r;
    r.x = pack2bf(f0.x, f0.y);
    r.y = pack2bf(f0.z, f0.w);
    r.z = pack2bf(f1.x, f1.y);
    r.w = pack2bf(f1.z, f1.w);
    return r;
}

// ---------------------------------------------------------------------------
// Pass 1 (MFMA, M-split, no w_lds): out = relu(Wf·(x⊙(Wg·s+2bg)) + bf + resid)
// R14 theory: R11's accidental 4.0 TB/s (spill streams) proves the DRAM
// pattern supports >4 TB/s; the limiter is independent request streams/CU.
// Blocks/CU was capped by the 18.4KB w_lds replica. Weights are L1-resident
// (32KB) -> load A-frags from global per GEMM (2xfloat4 + RNE pack). LDS
// drops to ~26KB -> 5-6 blocks/CU -> 5-6 overlapping staging streams.
// ---------------------------------------------------------------------------
__global__ void pass1(const float* __restrict__ x, const float* __restrict__ inj0,
                      const float* __restrict__ inj1, const float* __restrict__ resid,
                      const float* __restrict__ gate_w, const float* __restrict__ gate_b,
                      const float* __restrict__ fuse_w, const float* __restrict__ fuse_b,
                      float* __restrict__ out, float* __restrict__ partials)
{
    __shared__ uint32_t s_buf[32 * SSTRIDE];   // 16.9 KB: s (bf16 kpairs)
    __shared__ uint32_t a_buf[16 * SSTRIDE];   //  8.4 KB: acc slab / epi tile
    __shared__ float cinit[2][64];             // [0]=2*gate_b, [1]=fuse_b
    __shared__ float wred[8];                  // per-wave stats partials

    const int tid  = threadIdx.x;
    const int lane = tid & 63;
    const int w    = tid >> 6;     // wave 0..3
    const int g    = lane >> 4;    // k-group 0..3
    const int ln   = lane & 15;    // 0..15

    const int b    = blockIdx.x >> 8;
    const int lb   = blockIdx.x & 255;
    const int bCL  = b * (Cv * Lv);

    if (tid < 64) {
        cinit[0][tid] = 2.0f * gate_b[tid];
        cinit[1][tid] = fuse_b[tid];
    }

    float lsum = 0.0f, lsq = 0.0f;

    #pragma unroll 1
    for (int h = 0; h < 2; ++h) {
        const int col0 = lb * COLS + h * HALF;

        // ---- stage s = i0+i1+2x for all 64 ch of this half (12 f4 loads) ----
        #pragma unroll
        for (int uu = 0; uu < 4; ++uu) {
            const int u  = tid + uu * TPB;
            const int kp = u >> 5;               // 0..31 (ch pair)
            const int c  = (u & 31) << 2;        // col 0..124
            const int rA = bCL + (2 * kp) * Lv + col0 + c;
            const int rB = rA + Lv;
            const float4 xA = *reinterpret_cast<const float4*>(x    + rA);
            const float4 aA = *reinterpret_cast<const float4*>(inj0 + rA);
            const float4 bA = *reinterpret_cast<const float4*>(inj1 + rA);
            const float4 xB = *reinterpret_cast<const float4*>(x    + rB);
            const float4 aB = *reinterpret_cast<const float4*>(inj0 + rB);
            const float4 bB = *reinterpret_cast<const float4*>(inj1 + rB);
            uint4 dw;
            dw.x = pack2bf(aA.x + bA.x + 2.0f * xA.x, aB.x + bB.x + 2.0f * xB.x);
            dw.y = pack2bf(aA.y + bA.y + 2.0f * xA.y, aB.y + bB.y + 2.0f * xB.y);
            dw.z = pack2bf(aA.z + bA.z + 2.0f * xA.z, aB.z + bB.z + 2.0f * xB.z);
            dw.w = pack2bf(aA.w + bA.w + 2.0f * xA.w, aB.w + bB.w + 2.0f * xB.w);
            *reinterpret_cast<uint4*>(&s_buf[kp * SSTRIDE + c]) = dw;
        }
        __syncthreads();   // s (and on h=0: cinit) visible

        f32x4 D2[4][2];
        #pragma unroll
        for (int oc = 0; oc < 4; ++oc) {
            const float4 cb = *reinterpret_cast<const float4*>(&cinit[1][16 * oc + 4 * g]);
            D2[oc][0][0] = cb.x; D2[oc][0][1] = cb.y;
            D2[oc][0][2] = cb.z; D2[oc][0][3] = cb.w;
            D2[oc][1] = D2[oc][0];
        }

        // ==== two M-phases: gate rows 0-31 then 32-63 ====
        #pragma unroll 1
        for (int ph = 0; ph < 2; ++ph) {
            // ---- GEMM1: D1 = Wg[rows].s + 2bg (full K, A from global/L1) ----
            f32x4 D1[2][2];
            #pragma unroll
            for (int o2 = 0; o2 < 2; ++o2) {
                const int oc = 2 * ph + o2;
                const float4 cb = *reinterpret_cast<const float4*>(&cinit[0][16 * oc + 4 * g]);
                D1[o2][0][0] = cb.x; D1[o2][0][1] = cb.y;
                D1[o2][0][2] = cb.z; D1[o2][0][3] = cb.w;
                D1[o2][1] = D1[o2][0];
            }
            {
                uint4 A[2][2];   // [o2][kh]
                #pragma unroll
                for (int o2 = 0; o2 < 2; ++o2) {
                    const int m = ln + 16 * (2 * ph + o2);
                    A[o2][0] = load_wfrag(gate_w + m * 64 + 8 * g);
                    A[o2][1] = load_wfrag(gate_w + m * 64 + 32 + 8 * g);
                }
                #pragma unroll
                for (int nt = 0; nt < 2; ++nt) {
                    const int n = ln + 16 * (2 * w + nt);
                    uint4 B0, B1;
                    B0.x = s_buf[(4 * g + 0) * SSTRIDE + n];
                    B0.y = s_buf[(4 * g + 1) * SSTRIDE + n];
                    B0.z = s_buf[(4 * g + 2) * SSTRIDE + n];
                    B0.w = s_buf[(4 * g + 3) * SSTRIDE + n];
                    B1.x = s_buf[(16 + 4 * g + 0) * SSTRIDE + n];
                    B1.y = s_buf[(16 + 4 * g + 1) * SSTRIDE + n];
                    B1.z = s_buf[(16 + 4 * g + 2) * SSTRIDE + n];
                    B1.w = s_buf[(16 + 4 * g + 3) * SSTRIDE + n];
                    #pragma unroll
                    for (int o2 = 0; o2 < 2; ++o2) {
                        D1[o2][nt] = __builtin_amdgcn_mfma_f32_16x16x32_bf16(
                            __builtin_bit_cast(short8, A[o2][0]),
                            __builtin_bit_cast(short8, B0), D1[o2][nt], 0, 0, 0);
                        D1[o2][nt] = __builtin_amdgcn_mfma_f32_16x16x32_bf16(
                            __builtin_bit_cast(short8, A[o2][1]),
                            __builtin_bit_cast(short8, B1), D1[o2][nt], 0, 0, 0);
                    }
                }
            }

            // ---- acc = x*g for these 32 ch -> a_buf (x re-read, L2-hot) ----
            #pragma unroll
            for (int nt = 0; nt < 2; ++nt) {
                const int n  = ln + 16 * (2 * w + nt);
                const int cg = bCL + col0 + n;
                #pragma unroll
                for (int o2 = 0; o2 < 2; ++o2) {
                    const int m0 = 16 * (2 * ph + o2) + 4 * g;
                    float av[4];
                    #pragma unroll
                    for (int j = 0; j < 4; ++j)
                        av[j] = x[cg + (m0 + j) * Lv] * D1[o2][nt][j];
                    const int kpA = 8 * o2 + 2 * g;
                    a_buf[kpA * SSTRIDE + n]       = pack2bf(av[0], av[1]);
                    a_buf[(kpA + 1) * SSTRIDE + n] = pack2bf(av[2], av[3]);
                }
            }
            __syncthreads();   // a_buf visible

            // ---- GEMM2 partial-K: D2 += Wf[:, kslab] . acc ----
            {
                uint4 A2[4];
                #pragma unroll
                for (int oc = 0; oc < 4; ++oc) {
                    const int m = ln + 16 * oc;
                    A2[oc] = load_wfrag(fuse_w + m * 64 + 32 * ph + 8 * g);
                }
                #pragma unroll
                for (int nt = 0; nt < 2; ++nt) {
                    const int n = ln + 16 * (2 * w + nt);
                    uint4 Bf;
                    Bf.x = a_buf[(4 * g + 0) * SSTRIDE + n];
                    Bf.y = a_buf[(4 * g + 1) * SSTRIDE + n];
                    Bf.z = a_buf[(4 * g + 2) * SSTRIDE + n];
                    Bf.w = a_buf[(4 * g + 3) * SSTRIDE + n];
                    #pragma unroll
                    for (int oc = 0; oc < 4; ++oc)
                        D2[oc][nt] = __builtin_amdgcn_mfma_f32_16x16x32_bf16(
                            __builtin_bit_cast(short8, A2[oc]),
                            __builtin_bit_cast(short8, Bf), D2[oc][nt], 0, 0, 0);
                }
            }
            __syncthreads();   // GEMM2 reads done before a_buf overwrite
        }

        // ---- epilogue: 4 chunks of 16 rows via a_buf re-layout ----
        {
            float* uf = reinterpret_cast<float*>(a_buf);
            const int rowin = tid >> 4;          // 0..15
            const int cl    = tid & 15;          // 16 threads x 2 float4 per row
            #pragma unroll 1
            for (int ck = 0; ck < 4; ++ck) {
                #pragma unroll
                for (int nt = 0; nt < 2; ++nt) {
                    const int n = ln + 16 * (2 * w + nt);
                    #pragma unroll
                    for (int j = 0; j < 4; ++j)
                        uf[(4 * g + j) * SSTRIDE + n] = D2[ck][nt][j];
                }
                const int m   = 16 * ck + rowin;
                const int gbm = bCL + m * Lv + col0;
                const float4 ra = *reinterpret_cast<const float4*>(&resid[gbm + 4 * cl]);
                const float4 rb = *reinterpret_cast<const float4*>(&resid[gbm + 4 * cl + 64]);
                __syncthreads();
                float4 va = *reinterpret_cast<const float4*>(&uf[rowin * SSTRIDE + 4 * cl]);
                float4 vb = *reinterpret_cast<const float4*>(&uf[rowin * SSTRIDE + 4 * cl + 64]);
                va.x = fmaxf(va.x + ra.x, 0.0f); va.y = fmaxf(va.y + ra.y, 0.0f);
                va.z = fmaxf(va.z + ra.z, 0.0f); va.w = fmaxf(va.w + ra.w, 0.0f);
                vb.x = fmaxf(vb.x + rb.x, 0.0f); vb.y = fmaxf(vb.y + rb.y, 0.0f);
                vb.z = fmaxf(vb.z + rb.z, 0.0f); vb.w = fmaxf(vb.w + rb.w, 0.0f);
                *reinterpret_cast<float4*>(&out[gbm + 4 * cl])      = va;
                *reinterpret_cast<float4*>(&out[gbm + 4 * cl + 64]) = vb;
                lsum += (va.x + va.y) + (va.z + va.w) + (vb.x + vb.y) + (vb.z + vb.w);
                lsq = fmaf(va.x, va.x, lsq); lsq = fmaf(va.y, va.y, lsq);
                lsq = fmaf(va.z, va.z, lsq); lsq = fmaf(va.w, va.w, lsq);
                lsq = fmaf(vb.x, vb.x, lsq); lsq = fmaf(vb.y, vb.y, lsq);
                lsq = fmaf(vb.z, vb.z, lsq); lsq = fmaf(vb.w, vb.w, lsq);
                __syncthreads();   // chunk reads done before next writes
            }
        }
    }

    // ---- stats: wave shuffle reduce -> 4 partials -> thread 0 ----
    #pragma unroll
    for (int st = 1; st < 64; st <<= 1) {
        lsum += __shfl_xor(lsum, st);
        lsq  += __shfl_xor(lsq,  st);
    }
    if (lane == 0) { wred[2 * w] = lsum; wred[2 * w + 1] = lsq; }
    __syncthreads();
    if (tid == 0) {
        float s = 0.0f, q = 0.0f;
        #pragma unroll
        for (int i = 0; i < 4; ++i) { s += wred[2 * i]; q += wred[2 * i + 1]; }
        partials[2 * blockIdx.x]     = s;
        partials[2 * blockIdx.x + 1] = q;
    }
}

// ---------------------------------------------------------------------------
// Pass 2: reduce 256 partials per batch -> per-(b,c) scale/bias.
// ---------------------------------------------------------------------------
__global__ __launch_bounds__(256)
void pass2(const float* __restrict__ partials, const float* __restrict__ gn_w,
           const float* __restrict__ gn_b, float* __restrict__ sb)
{
    __shared__ float r1[256], r2[256];
    __shared__ float mean_s, rs_s;
    const int b = blockIdx.x, tid = threadIdx.x;
    r1[tid] = partials[2 * (b * 256 + tid)];
    r2[tid] = partials[2 * (b * 256 + tid) + 1];
    __syncthreads();
    #pragma unroll
    for (int st = 128; st > 0; st >>= 1) {
        if (tid < st) { r1[tid] += r1[tid + st]; r2[tid] += r2[tid + st]; }
        __syncthreads();
    }
    if (tid == 0) {
        const float n = (float)Cv * (float)Lv;
        const float mean = r1[0] / n;
        const float var  = r2[0] / n - mean * mean;
        mean_s = mean;
        rs_s   = rsqrtf(var + 1e-5f);
    }
    __syncthreads();
    if (tid < Cv) {
        const float sc = gn_w[tid] * rs_s;
        sb[b * Cv + tid]           = sc;
        sb[Bv * Cv + b * Cv + tid] = fmaf(-mean_s, sc, gn_b[tid]);
    }
}

// ---------------------------------------------------------------------------
// Pass 3: in-place GroupNorm affine on d_out (float4 vectorized).
// ---------------------------------------------------------------------------
__global__ __launch_bounds__(256)
void pass3(float* __restrict__ out, const float* __restrict__ sb)
{
    const int total4 = (Bv * Cv * Lv) / 4;   // 8388608
    for (int i = blockIdx.x * blockDim.x + threadIdx.x; i < total4;
         i += gridDim.x * blockDim.x) {
        const int row = i >> 14;            // / (L/4): row = b*64 + c
        const float sc = sb[row];
        const float bi = sb[Bv * Cv + row];
        float4 v = reinterpret_cast<float4*>(out)[i];
        v.x = fmaf(v.x, sc, bi);
        v.y = fmaf(v.y, sc, bi);
        v.z = fmaf(v.z, sc, bi);
        v.w = fmaf(v.w, sc, bi);
        reinterpret_cast<float4*>(out)[i] = v;
    }
}

extern "C" void kernel_launch(void* const* d_in, const int* in_sizes, int n_in,
                              void* d_out, int out_size, void* d_ws, size_t ws_size,
                              hipStream_t stream)
{
    const float* x      = (const float*)d_in[0];
    const float* inj0   = (const float*)d_in[1];
    const float* inj1   = (const float*)d_in[2];
    const float* resid  = (const float*)d_in[3];
    const float* gate_w = (const float*)d_in[4];
    const float* gate_b = (const float*)d_in[5];
    const float* fuse_w = (const float*)d_in[6];
    const float* fuse_b = (const float*)d_in[7];
    const float* gn_w   = (const float*)d_in[8];
    const float* gn_b   = (const float*)d_in[9];

    float* out      = (float*)d_out;
    float* ws       = (float*)d_ws;
    float* partials = ws;                 // 2 * 2048 floats = 16 KiB
    float* sb       = ws + 2 * GRID1;     // 2 * 512 floats  =  4 KiB

    hipLaunchKernelGGL(pass1, dim3(GRID1), dim3(TPB), 0, stream,
                       x, inj0, inj1, resid, gate_w, gate_b, fuse_w, fuse_b,
                       out, partials);
    hipLaunchKernelGGL(pass2, dim3(Bv), dim3(256), 0, stream,
                       partials, gn_w, gn_b, sb);
    hipLaunchKernelGGL(pass3, dim3(2048), dim3(256), 0, stream, out, sb);
}

// Round 15
// 186.590 us; speedup vs baseline: 1.1408x; 1.1408x over previous
//
#include <hip/hip_runtime.h>
#include <stdint.h>

#define Bv 8
#define Cv 64
#define Lv 65536
#define TPB 512
#define HALF 128                      // cols per half-tile
#define COLS 256                      // cols per block (2 halves)
#define BLKS_PER_B (Lv / COLS)        // 256
#define GRID1 (Bv * BLKS_PER_B)       // 2048

// workspace: partials 2*2048 floats (16 KiB) + sb 1024 floats (4 KiB) = 20 KiB

typedef __attribute__((ext_vector_type(8))) short short8;
typedef __attribute__((ext_vector_type(4))) float f32x4;

#define SSTRIDE 132   // dwords per row

__device__ __forceinline__ uint16_t f2bf(float f) {
    uint32_t u = __float_as_uint(f);
    uint32_t r = u + 0x7FFFu + ((u >> 16) & 1u);   // round-to-nearest-even
    return (uint16_t)(r >> 16);
}
__device__ __forceinline__ uint32_t pack2bf(float lo, float hi) {
    return (uint32_t)f2bf(lo) | ((uint32_t)f2bf(hi) << 16);
}

// ---------------------------------------------------------------------------
// Pass 1 (MFMA, nt=1, double-buffered): out = relu(Wf·(x⊙(Wg·s+2bg))+bf+resid)
// R15 theory: per-block wall time 43us vs 18us of HBM transfer -> ~25us of
// serial latency during which HBM idles (only 2-3 blocks/CU to cover it).
// Fix = intra-block pipeline: (1) s_buf[2] double buffer, stage(h+1) issued
// right after GEMM1(h) — its vmcnt drain lands at the epilogue barrier;
// (2) x for acc prefetched at half-entry (hides under GEMM1);
// (3) barriers 7->4 per half (acc->GEMM2 and GEMM2->epiwrite are
// wave-column-slab-local; verified B-frags touch only col n = 16w+ln).
// ---------------------------------------------------------------------------
__global__ void pass1(const float* __restrict__ x, const float* __restrict__ inj0,
                      const float* __restrict__ inj1, const float* __restrict__ resid,
                      const float* __restrict__ gate_w, const float* __restrict__ gate_b,
                      const float* __restrict__ fuse_w, const float* __restrict__ fuse_b,
                      float* __restrict__ out, float* __restrict__ partials)
{
    __shared__ uint32_t s_buf[2][32 * SSTRIDE];    // 33.8 KB (s / acc / epi tile)
    __shared__ uint32_t w_lds[2][64][36];          // 18.4 KB
    __shared__ float cinit[2][64];                 // [0]=2*gate_b, [1]=fuse_b
    __shared__ float wred[16];                     // per-wave stats partials

    const int tid  = threadIdx.x;
    const int lane = tid & 63;
    const int w    = tid >> 6;     // wave 0..7
    const int g    = lane >> 4;    // k-group 0..3
    const int ln   = lane & 15;    // 0..15
    const int n    = 16 * w + ln;  // wave's column within the half

    const int b    = blockIdx.x >> 8;
    const int lb   = blockIdx.x & 255;
    const int bCL  = b * (Cv * Lv);
    const int tile0 = lb * COLS;

    // stage s = i0+i1+2x for one 128-col half into s_buf[dst]
    auto stage_half = [&](int dst, int scol) {
        #pragma unroll
        for (int uu = 0; uu < 2; ++uu) {
            const int u  = tid + uu * TPB;
            const int kp = u >> 5;               // 0..31 (ch pair)
            const int c  = (u & 31) << 2;        // col 0..124
            const int rA = bCL + (2 * kp) * Lv + scol + c;
            const int rB = rA + Lv;
            const float4 xA = *reinterpret_cast<const float4*>(x    + rA);
            const float4 aA = *reinterpret_cast<const float4*>(inj0 + rA);
            const float4 bA = *reinterpret_cast<const float4*>(inj1 + rA);
            const float4 xB = *reinterpret_cast<const float4*>(x    + rB);
            const float4 aB = *reinterpret_cast<const float4*>(inj0 + rB);
            const float4 bB = *reinterpret_cast<const float4*>(inj1 + rB);
            uint4 dw;
            dw.x = pack2bf(aA.x + bA.x + 2.0f * xA.x, aB.x + bB.x + 2.0f * xB.x);
            dw.y = pack2bf(aA.y + bA.y + 2.0f * xA.y, aB.y + bB.y + 2.0f * xB.y);
            dw.z = pack2bf(aA.z + bA.z + 2.0f * xA.z, aB.z + bB.z + 2.0f * xB.z);
            dw.w = pack2bf(aA.w + bA.w + 2.0f * xA.w, aB.w + bB.w + 2.0f * xB.w);
            *reinterpret_cast<uint4*>(&s_buf[dst][kp * SSTRIDE + c]) = dw;
        }
    };

    // ---- stage weights + cinit + first half (one big independent burst) ----
    {
        const int mat = tid >> 8;              // 0=gate, 1=fuse
        const int m   = (tid >> 2) & 63;
        const int k0  = (tid & 3) << 4;
        const float* wsrc = mat ? fuse_w : gate_w;
        const float4* w4 = reinterpret_cast<const float4*>(wsrc + m * 64 + k0);
        uint32_t* dst = &w_lds[mat][m][k0 >> 1];
        #pragma unroll
        for (int q = 0; q < 4; ++q) {
            const float4 v = w4[q];
            dst[2 * q]     = pack2bf(v.x, v.y);
            dst[2 * q + 1] = pack2bf(v.z, v.w);
        }
        if (tid < 64) {
            cinit[0][tid] = 2.0f * gate_b[tid];
            cinit[1][tid] = fuse_b[tid];
        }
    }
    stage_half(0, tile0);
    __syncthreads();   // weights, cinit, s_buf[0] visible

    float lsum = 0.0f, lsq = 0.0f;

    #pragma unroll 1
    for (int h = 0; h < 2; ++h) {
        const int cur  = h;
        const int col0 = tile0 + h * HALF;

        // ---- x prefetch for acc (16 scalars; hides under GEMM1) ----
        float xp[16];
        {
            const int cg = bCL + col0 + n;
            #pragma unroll
            for (int oc = 0; oc < 4; ++oc)
                #pragma unroll
                for (int j = 0; j < 4; ++j)
                    xp[4 * oc + j] = x[cg + (16 * oc + 4 * g + j) * Lv];
        }

        // ---- GEMM1: D1 = Wg . s + 2bg  (full K, 8 MFMA) ----
        f32x4 D1[4];
        #pragma unroll
        for (int oc = 0; oc < 4; ++oc) {
            const float4 cb = *reinterpret_cast<const float4*>(&cinit[0][16 * oc + 4 * g]);
            D1[oc][0] = cb.x; D1[oc][1] = cb.y; D1[oc][2] = cb.z; D1[oc][3] = cb.w;
        }
        {
            uint4 B0, B1;
            B0.x = s_buf[cur][(4 * g + 0) * SSTRIDE + n];
            B0.y = s_buf[cur][(4 * g + 1) * SSTRIDE + n];
            B0.z = s_buf[cur][(4 * g + 2) * SSTRIDE + n];
            B0.w = s_buf[cur][(4 * g + 3) * SSTRIDE + n];
            B1.x = s_buf[cur][(16 + 4 * g + 0) * SSTRIDE + n];
            B1.y = s_buf[cur][(16 + 4 * g + 1) * SSTRIDE + n];
            B1.z = s_buf[cur][(16 + 4 * g + 2) * SSTRIDE + n];
            B1.w = s_buf[cur][(16 + 4 * g + 3) * SSTRIDE + n];
            #pragma unroll
            for (int oc = 0; oc < 4; ++oc) {
                const int m = ln + 16 * oc;
                const uint4 A0 = *reinterpret_cast<const uint4*>(&w_lds[0][m][4 * g]);
                const uint4 A1 = *reinterpret_cast<const uint4*>(&w_lds[0][m][16 + 4 * g]);
                D1[oc] = __builtin_amdgcn_mfma_f32_16x16x32_bf16(
                    __builtin_bit_cast(short8, A0), __builtin_bit_cast(short8, B0),
                    D1[oc], 0, 0, 0);
                D1[oc] = __builtin_amdgcn_mfma_f32_16x16x32_bf16(
                    __builtin_bit_cast(short8, A1), __builtin_bit_cast(short8, B1),
                    D1[oc], 0, 0, 0);
            }
        }

        // ---- issue next half's staging NOW (drains at epilogue barrier) ----
        if (h == 0) stage_half(1, tile0 + HALF);

        // ---- acc = x*g -> in-place into s_buf[cur] (own 16-col slab) ----
        #pragma unroll
        for (int oc = 0; oc < 4; ++oc) {
            float av[4];
            #pragma unroll
            for (int j = 0; j < 4; ++j)
                av[j] = xp[4 * oc + j] * D1[oc][j];
            const int kp = 8 * oc + 2 * g;
            s_buf[cur][kp * SSTRIDE + n]       = pack2bf(av[0], av[1]);
            s_buf[cur][(kp + 1) * SSTRIDE + n] = pack2bf(av[2], av[3]);
        }
        // no barrier: acc writes and GEMM2 reads are wave-slab-local (col n)

        // ---- GEMM2: D2 = Wf . acc + fuse_b  (full K, 8 MFMA) ----
        f32x4 D2[4];
        #pragma unroll
        for (int oc = 0; oc < 4; ++oc) {
            const float4 cb = *reinterpret_cast<const float4*>(&cinit[1][16 * oc + 4 * g]);
            D2[oc][0] = cb.x; D2[oc][1] = cb.y; D2[oc][2] = cb.z; D2[oc][3] = cb.w;
        }
        {
            uint4 B0, B1;
            B0.x = s_buf[cur][(4 * g + 0) * SSTRIDE + n];
            B0.y = s_buf[cur][(4 * g + 1) * SSTRIDE + n];
            B0.z = s_buf[cur][(4 * g + 2) * SSTRIDE + n];
            B0.w = s_buf[cur][(4 * g + 3) * SSTRIDE + n];
            B1.x = s_buf[cur][(16 + 4 * g + 0) * SSTRIDE + n];
            B1.y = s_buf[cur][(16 + 4 * g + 1) * SSTRIDE + n];
            B1.z = s_buf[cur][(16 + 4 * g + 2) * SSTRIDE + n];
            B1.w = s_buf[cur][(16 + 4 * g + 3) * SSTRIDE + n];
            #pragma unroll
            for (int oc = 0; oc < 4; ++oc) {
                const int m = ln + 16 * oc;
                const uint4 A0 = *reinterpret_cast<const uint4*>(&w_lds[1][m][4 * g]);
                const uint4 A1 = *reinterpret_cast<const uint4*>(&w_lds[1][m][16 + 4 * g]);
                D2[oc] = __builtin_amdgcn_mfma_f32_16x16x32_bf16(
                    __builtin_bit_cast(short8, A0), __builtin_bit_cast(short8, B0),
                    D2[oc], 0, 0, 0);
                D2[oc] = __builtin_amdgcn_mfma_f32_16x16x32_bf16(
                    __builtin_bit_cast(short8, A1), __builtin_bit_cast(short8, B1),
                    D2[oc], 0, 0, 0);
            }
        }
        // no barrier: epi-writes below are also wave-slab-local

        // ---- epilogue: 2 chunks of 32 rows via s_buf[cur] re-layout ----
        {
            float* uf = reinterpret_cast<float*>(s_buf[cur]);
            const int rowin = tid >> 4;          // 0..31
            const int cl    = tid & 15;          // 16 threads x 2 float4 per row
            #pragma unroll 1
            for (int ck = 0; ck < 2; ++ck) {
                #pragma unroll
                for (int oc2 = 0; oc2 < 2; ++oc2) {
                    const int oc = 2 * ck + oc2;
                    #pragma unroll
                    for (int j = 0; j < 4; ++j)
                        uf[(16 * oc2 + 4 * g + j) * SSTRIDE + n] = D2[oc][j];
                }
                const int m   = 32 * ck + rowin;
                const int gbm = bCL + m * Lv + col0;
                const float4 ra = *reinterpret_cast<const float4*>(&resid[gbm + 4 * cl]);
                const float4 rb = *reinterpret_cast<const float4*>(&resid[gbm + 4 * cl + 64]);
                __syncthreads();   // all epi-writes visible (also drains stage loads)
                float4 va = *reinterpret_cast<const float4*>(&uf[rowin * SSTRIDE + 4 * cl]);
                float4 vb = *reinterpret_cast<const float4*>(&uf[rowin * SSTRIDE + 4 * cl + 64]);
                va.x = fmaxf(va.x + ra.x, 0.0f); va.y = fmaxf(va.y + ra.y, 0.0f);
                va.z = fmaxf(va.z + ra.z, 0.0f); va.w = fmaxf(va.w + ra.w, 0.0f);
                vb.x = fmaxf(vb.x + rb.x, 0.0f); vb.y = fmaxf(vb.y + rb.y, 0.0f);
                vb.z = fmaxf(vb.z + rb.z, 0.0f); vb.w = fmaxf(vb.w + rb.w, 0.0f);
                *reinterpret_cast<float4*>(&out[gbm + 4 * cl])      = va;
                *reinterpret_cast<float4*>(&out[gbm + 4 * cl + 64]) = vb;
                lsum += (va.x + va.y) + (va.z + va.w) + (vb.x + vb.y) + (vb.z + vb.w);
                lsq = fmaf(va.x, va.x, lsq); lsq = fmaf(va.y, va.y, lsq);
                lsq = fmaf(va.z, va.z, lsq); lsq = fmaf(va.w, va.w, lsq);
                lsq = fmaf(vb.x, vb.x, lsq); lsq = fmaf(vb.y, vb.y, lsq);
                lsq = fmaf(vb.z, vb.z, lsq); lsq = fmaf(vb.w, vb.w, lsq);
                __syncthreads();   // chunk reads done before next writes / next half
            }
        }
    }

    // ---- stats: wave shuffle reduce -> 8 partials -> thread 0 ----
    #pragma unroll
    for (int st = 1; st < 64; st <<= 1) {
        lsum += __shfl_xor(lsum, st);
        lsq  += __shfl_xor(lsq,  st);
    }
    if (lane == 0) { wred[2 * w] = lsum; wred[2 * w + 1] = lsq; }
    __syncthreads();
    if (tid == 0) {
        float s = 0.0f, q = 0.0f;
        #pragma unroll
        for (int i = 0; i < 8; ++i) { s += wred[2 * i]; q += wred[2 * i + 1]; }
        partials[2 * blockIdx.x]     = s;
        partials[2 * blockIdx.x + 1] = q;
    }
}

// ---------------------------------------------------------------------------
// Pass 2: reduce 256 partials per batch -> per-(b,c) scale/bias.
// ---------------------------------------------------------------------------
__global__ __launch_bounds__(256)
void pass2(const float* __restrict__ partials, const float* __restrict__ gn_w,
           const float* __restrict__ gn_b, float* __restrict__ sb)
{
    __shared__ float r1[256], r2[256];
    __shared__ float mean_s, rs_s;
    const int b = blockIdx.x, tid = threadIdx.x;
    r1[tid] = partials[2 * (b * 256 + tid)];
    r2[tid] = partials[2 * (b * 256 + tid) + 1];
    __syncthreads();
    #pragma unroll
    for (int st = 128; st > 0; st >>= 1) {
        if (tid < st) { r1[tid] += r1[tid + st]; r2[tid] += r2[tid + st]; }
        __syncthreads();
    }
    if (tid == 0) {
        const float n = (float)Cv * (float)Lv;
        const float mean = r1[0] / n;
        const float var  = r2[0] / n - mean * mean;
        mean_s = mean;
        rs_s   = rsqrtf(var + 1e-5f);
    }
    __syncthreads();
    if (tid < Cv) {
        const float sc = gn_w[tid] * rs_s;
        sb[b * Cv + tid]           = sc;
        sb[Bv * Cv + b * Cv + tid] = fmaf(-mean_s, sc, gn_b[tid]);
    }
}

// ---------------------------------------------------------------------------
// Pass 3: in-place GroupNorm affine on d_out (float4 vectorized).
// ---------------------------------------------------------------------------
__global__ __launch_bounds__(256)
void pass3(float* __restrict__ out, const float* __restrict__ sb)
{
    const int total4 = (Bv * Cv * Lv) / 4;   // 8388608
    for (int i = blockIdx.x * blockDim.x + threadIdx.x; i < total4;
         i += gridDim.x * blockDim.x) {
        const int row = i >> 14;            // / (L/4): row = b*64 + c
        const float sc = sb[row];
        const float bi = sb[Bv * Cv + row];
        float4 v = reinterpret_cast<float4*>(out)[i];
        v.x = fmaf(v.x, sc, bi);
        v.y = fmaf(v.y, sc, bi);
        v.z = fmaf(v.z, sc, bi);
        v.w = fmaf(v.w, sc, bi);
        reinterpret_cast<float4*>(out)[i] = v;
    }
}

extern "C" void kernel_launch(void* const* d_in, const int* in_sizes, int n_in,
                              void* d_out, int out_size, void* d_ws, size_t ws_size,
                              hipStream_t stream)
{
    const float* x      = (const float*)d_in[0];
    const float* inj0   = (const float*)d_in[1];
    const float* inj1   = (const float*)d_in[2];
    const float* resid  = (const float*)d_in[3];
    const float* gate_w = (const float*)d_in[4];
    const float* gate_b = (const float*)d_in[5];
    const float* fuse_w = (const float*)d_in[6];
    const float* fuse_b = (const float*)d_in[7];
    const float* gn_w   = (const float*)d_in[8];
    const float* gn_b   = (const float*)d_in[9];

    float* out      = (float*)d_out;
    float* ws       = (float*)d_ws;
    float* partials = ws;                 // 2 * 2048 floats = 16 KiB
    float* sb       = ws + 2 * GRID1;     // 2 * 512 floats  =  4 KiB

    hipLaunchKernelGGL(pass1, dim3(GRID1), dim3(TPB), 0, stream,
                       x, inj0, inj1, resid, gate_w, gate_b, fuse_w, fuse_b,
                       out, partials);
    hipLaunchKernelGGL(pass2, dim3(Bv), dim3(256), 0, stream,
                       partials, gn_w, gn_b, sb);
    hipLaunchKernelGGL(pass3, dim3(2048), dim3(256), 0, stream, out, sb);
}